// Round 6
// baseline (477.926 us; speedup 1.0000x reference)
//
#include <hip/hip_runtime.h>
#include <math.h>

#define F1 16
#define F2 8

// degree count via atomics (deg pre-zeroed)
__global__ void k_deg(const int* __restrict__ dst, float* __restrict__ deg, int E) {
    int e = blockIdx.x * blockDim.x + threadIdx.x;
    if (e < E) atomicAdd(&deg[dst[e]], 1.0f);
}

// hybrid: blocks [0,FB) zero out4[f0,f1); blocks [FB,..) do conv1 edge atomics
__global__ void k_conv1_fill(const int* __restrict__ src, const int* __restrict__ dst,
                             const float* __restrict__ deg, const float* __restrict__ W1,
                             float* __restrict__ x1, float4* __restrict__ out4,
                             long f0, long f1, int E, int FB) {
    if ((int)blockIdx.x < FB) {
        const float4 z = make_float4(0.f, 0.f, 0.f, 0.f);
        long stride = (long)FB * blockDim.x;
        for (long i = f0 + (long)blockIdx.x * blockDim.x + threadIdx.x; i < f1; i += stride)
            out4[i] = z;
    } else {
        long id = (long)(blockIdx.x - FB) * blockDim.x + threadIdx.x;
        long e = id >> 4;
        int f = (int)(id & (F1 - 1));
        if (e < E) {
            int s = src[e], d = dst[e];
            float nrm = rsqrtf((deg[s] + 1.0f) * (deg[d] + 1.0f));
            atomicAdd(&x1[(long)d * F1 + f], nrm * W1[(long)s * F1 + f]);
        }
    }
}

// hybrid: fill + layer1 (relu + 16x8 matmul), (node,out-feature)-parallel
__global__ void k_layer1_fill(const float* __restrict__ deg, const float* __restrict__ b1,
                              const float* __restrict__ W1, const float* __restrict__ W2,
                              const float* __restrict__ x1, float* __restrict__ h2,
                              float4* __restrict__ out4, long f0, long f1,
                              int N, int FB) {
    if ((int)blockIdx.x < FB) {
        const float4 z = make_float4(0.f, 0.f, 0.f, 0.f);
        long stride = (long)FB * blockDim.x;
        for (long i = f0 + (long)blockIdx.x * blockDim.x + threadIdx.x; i < f1; i += stride)
            out4[i] = z;
    } else {
        int id = (int)((blockIdx.x - FB) * blockDim.x + threadIdx.x);
        if (id < N * F2) {
            int i = id >> 3;
            int g = id & (F2 - 1);
            float sw = 1.0f / (deg[i] + 1.0f);
            float acc = 0.0f;
            #pragma unroll
            for (int f = 0; f < F1; ++f) {
                float v = x1[(long)i * F1 + f] + sw * W1[(long)i * F1 + f] + b1[f];
                v = v > 0.0f ? v : 0.0f;
                acc += v * W2[f * F2 + g];
            }
            h2[(long)i * F2 + g] = acc;
        }
    }
}

// hybrid: fill + conv2 edge atomics
__global__ void k_conv2_fill(const int* __restrict__ src, const int* __restrict__ dst,
                             const float* __restrict__ deg, const float* __restrict__ h2,
                             float* __restrict__ x2, float4* __restrict__ out4,
                             long f0, long f1, int E, int FB) {
    if ((int)blockIdx.x < FB) {
        const float4 z = make_float4(0.f, 0.f, 0.f, 0.f);
        long stride = (long)FB * blockDim.x;
        for (long i = f0 + (long)blockIdx.x * blockDim.x + threadIdx.x; i < f1; i += stride)
            out4[i] = z;
    } else {
        long id = (long)(blockIdx.x - FB) * blockDim.x + threadIdx.x;
        long e = id >> 3;
        int g = (int)(id & (F2 - 1));
        if (e < E) {
            int s = src[e], d = dst[e];
            float nrm = rsqrtf((deg[s] + 1.0f) * (deg[d] + 1.0f));
            atomicAdd(&x2[(long)d * F2 + g], nrm * h2[(long)s * F2 + g]);
        }
    }
}

// fused epilogue: threads [0,U) score+scatter orient at mutual pairs;
// threads [U,U+E) write 1.0 at non-mutual directed edges (reverse absent in
// the pristine adjacency) — disjoint from orient's addresses, so no ordering.
__global__ void k_orient_ones(const int2* __restrict__ ue, const int* __restrict__ src,
                              const int* __restrict__ dst, const float* __restrict__ adj,
                              const float* __restrict__ x2, const float* __restrict__ h2,
                              const float* __restrict__ deg, const float* __restrict__ b2,
                              const float* __restrict__ Wfc, const float* __restrict__ bfc,
                              float* __restrict__ out, int U, int E, int N) {
    int k = blockIdx.x * blockDim.x + threadIdx.x;
    if (k < U) {
        int2 e = ue[k];
        int u = e.x, v = e.y;
        float swu = 1.0f / (deg[u] + 1.0f);
        float swv = 1.0f / (deg[v] + 1.0f);
        float s = bfc[0];
        #pragma unroll
        for (int g = 0; g < F2; ++g) {
            float xu = x2[(long)u * F2 + g] + swu * h2[(long)u * F2 + g] + b2[g];
            float xv = x2[(long)v * F2 + g] + swv * h2[(long)v * F2 + g] + b2[g];
            xu = xu > 0.0f ? xu : 0.0f;
            xv = xv > 0.0f ? xv : 0.0f;
            s += xu * Wfc[g] + xv * Wfc[F2 + g];
        }
        float orient = 1.0f / (1.0f + expf(-s));
        out[(long)u * N + v] = orient;
        out[(long)v * N + u] = 1.0f - orient;
    } else if (k < U + E) {
        int e = k - U;
        int s = src[e], d = dst[e];
        if (adj[(long)d * N + s] == 0.0f)
            out[(long)s * N + d] = 1.0f;
    }
}

extern "C" void kernel_launch(void* const* d_in, const int* in_sizes, int n_in,
                              void* d_out, int out_size, void* d_ws, size_t ws_size,
                              hipStream_t stream) {
    const float* adj = (const float*)d_in[0];
    const float* W1  = (const float*)d_in[1];
    const float* b1  = (const float*)d_in[2];
    const float* W2  = (const float*)d_in[3];
    const float* b2  = (const float*)d_in[4];
    const float* Wfc = (const float*)d_in[5];
    const float* bfc = (const float*)d_in[6];
    const int* edge_index = (const int*)d_in[7];
    const int2* und       = (const int2*)d_in[8];

    int N = in_sizes[1] / F1;      // 8192
    int E = in_sizes[7] / 2;
    int U = in_sizes[8] / 2;
    const int* src = edge_index;
    const int* dst = edge_index + E;

    // ws layout: [deg(N) | x1(16N) | x2(8N)] (zeroed) | h2(8N) (written before read)
    float* ws  = (float*)d_ws;
    float* deg = ws;
    float* x1  = ws + N;
    float* x2  = x1 + (long)F1 * N;
    float* h2  = x2 + (long)F2 * N;

    float4* out4 = (float4*)d_out;
    const long Z4 = (long)N * N / 4;
    const long c1 = Z4 / 3, c2 = Z4 * 2 / 3;

    const int B = 256;
    const int FB = 2048;   // fill blocks per hybrid kernel

    // zero deg + x1 + x2 (800 KB)
    hipMemsetAsync(d_ws, 0, (size_t)(N + (long)F1 * N + (long)F2 * N) * sizeof(float), stream);

    // degree count
    k_deg<<<(E + B - 1) / B, B, 0, stream>>>(dst, deg, E);

    // conv1 atomics || zero-fill out chunk 1/3
    {
        int cb = (int)(((long)E * F1 + B - 1) / B);
        k_conv1_fill<<<FB + cb, B, 0, stream>>>(src, dst, deg, W1, x1, out4, 0, c1, E, FB);
    }
    // layer1 || zero-fill chunk 2/3
    {
        int cb = (N * F2 + B - 1) / B;
        k_layer1_fill<<<FB + cb, B, 0, stream>>>(deg, b1, W1, W2, x1, h2, out4, c1, c2, N, FB);
    }
    // conv2 atomics || zero-fill chunk 3/3
    {
        int cb = (int)(((long)E * F2 + B - 1) / B);
        k_conv2_fill<<<FB + cb, B, 0, stream>>>(src, dst, deg, h2, x2, out4, c2, Z4, E, FB);
    }
    // orient + selective ones (disjoint writes; needs full fill + conv2)
    k_orient_ones<<<(U + E + B - 1) / B, B, 0, stream>>>(und, src, dst, adj, x2, h2, deg,
                                                         b2, Wfc, bfc, (float*)d_out,
                                                         U, E, N);
}

// Round 7
// 448.127 us; speedup vs baseline: 1.0665x; 1.0665x over previous
//
#include <hip/hip_runtime.h>
#include <math.h>

#define F1 16
#define F2 8

// Fused: scatter 1.0 at every directed edge position of out AND count in-degree.
__global__ void k_edges0(const int* __restrict__ src, const int* __restrict__ dst,
                         float* __restrict__ out, float* __restrict__ deg,
                         int E, int N) {
    int e = blockIdx.x * blockDim.x + threadIdx.x;
    if (e < E) {
        int s = src[e], d = dst[e];
        out[(long)s * N + d] = 1.0f;
        atomicAdd(&deg[d], 1.0f);
    }
}

// conv1 aggregation: x1[dst] += norm * W1[src]; norm computed inline from deg.
// (x1 pre-zeroed by memset; deg holds in-degree counts, +1 for self-loop)
__global__ void k_conv1_edges(const int* __restrict__ src, const int* __restrict__ dst,
                              const float* __restrict__ deg, const float* __restrict__ W1,
                              float* __restrict__ x1, int E) {
    int id = blockIdx.x * blockDim.x + threadIdx.x;
    int e = id >> 4;
    int f = id & (F1 - 1);
    if (e < E) {
        int s = src[e], d = dst[e];
        float nrm = rsqrtf((deg[s] + 1.0f) * (deg[d] + 1.0f));
        atomicAdd(&x1[(long)d * F1 + f], nrm * W1[(long)s * F1 + f]);
    }
}

// Per (node, out-feature): r = relu(x1 + W1/(deg+1) + b1); h2[i,g] = sum_f r[f]*W2[f,g]
__global__ void k_layer1(const float* __restrict__ deg, const float* __restrict__ b1,
                         const float* __restrict__ W1, const float* __restrict__ W2,
                         const float* __restrict__ x1, float* __restrict__ h2, int N) {
    int id = blockIdx.x * blockDim.x + threadIdx.x;
    if (id < N * F2) {
        int i = id >> 3;        // node
        int g = id & (F2 - 1);  // out feature
        float sw = 1.0f / (deg[i] + 1.0f);
        float acc = 0.0f;
        #pragma unroll
        for (int f = 0; f < F1; ++f) {
            float v = x1[(long)i * F1 + f] + sw * W1[(long)i * F1 + f] + b1[f];
            v = v > 0.0f ? v : 0.0f;
            acc += v * W2[f * F2 + g];
        }
        h2[(long)i * F2 + g] = acc;
    }
}

// conv2 aggregation: x2[dst] += norm * h2[src]; norm inline from deg.
__global__ void k_conv2_edges(const int* __restrict__ src, const int* __restrict__ dst,
                              const float* __restrict__ deg, const float* __restrict__ h2,
                              float* __restrict__ x2, int E) {
    int id = blockIdx.x * blockDim.x + threadIdx.x;
    int e = id >> 3;
    int g = id & (F2 - 1);
    if (e < E) {
        int s = src[e], d = dst[e];
        float nrm = rsqrtf((deg[s] + 1.0f) * (deg[d] + 1.0f));
        atomicAdd(&x2[(long)d * F2 + g], nrm * h2[(long)s * F2 + g]);
    }
}

// Per undirected edge: finish conv2 (self term + bias + relu) inline, score, scatter.
__global__ void k_orient(const int2* __restrict__ ue, const float* __restrict__ x2,
                         const float* __restrict__ h2, const float* __restrict__ deg,
                         const float* __restrict__ b2, const float* __restrict__ Wfc,
                         const float* __restrict__ bfc, float* __restrict__ out,
                         int U, int N) {
    int k = blockIdx.x * blockDim.x + threadIdx.x;
    if (k < U) {
        int2 e = ue[k];
        int u = e.x, v = e.y;
        float swu = 1.0f / (deg[u] + 1.0f);
        float swv = 1.0f / (deg[v] + 1.0f);
        float s = bfc[0];
        #pragma unroll
        for (int g = 0; g < F2; ++g) {
            float xu = x2[(long)u * F2 + g] + swu * h2[(long)u * F2 + g] + b2[g];
            float xv = x2[(long)v * F2 + g] + swv * h2[(long)v * F2 + g] + b2[g];
            xu = xu > 0.0f ? xu : 0.0f;
            xv = xv > 0.0f ? xv : 0.0f;
            s += xu * Wfc[g] + xv * Wfc[F2 + g];
        }
        float orient = 1.0f / (1.0f + expf(-s));
        out[(long)u * N + v] = orient;
        out[(long)v * N + u] = 1.0f - orient;
    }
}

extern "C" void kernel_launch(void* const* d_in, const int* in_sizes, int n_in,
                              void* d_out, int out_size, void* d_ws, size_t ws_size,
                              hipStream_t stream) {
    const float* W1  = (const float*)d_in[1];
    const float* b1  = (const float*)d_in[2];
    const float* W2  = (const float*)d_in[3];
    const float* b2  = (const float*)d_in[4];
    const float* Wfc = (const float*)d_in[5];
    const float* bfc = (const float*)d_in[6];
    const int* edge_index = (const int*)d_in[7];
    const int2* und       = (const int2*)d_in[8];

    int N = in_sizes[1] / F1;      // 8192
    int E = in_sizes[7] / 2;
    int U = in_sizes[8] / 2;
    const int* src = edge_index;
    const int* dst = edge_index + E;

    // ws layout: [deg(N) | x1(16N) | x2(8N)] (zeroed) | h2(8N) (written before read)
    float* ws  = (float*)d_ws;
    float* deg = ws;
    float* x1  = ws + N;
    float* x2  = x1 + (long)F1 * N;
    float* h2  = x2 + (long)F2 * N;

    const int B = 256;

    // Zero output (write-only; adjacency reconstructed exactly from edge_index
    // since A is 0/1 and edge_index = nonzero(A)).
    hipMemsetAsync(d_out, 0, (size_t)N * N * sizeof(float), stream);
    // Zero deg + x1 + x2 in one contiguous memset (800 KB).
    hipMemsetAsync(d_ws, 0, (size_t)(N + (long)F1 * N + (long)F2 * N) * sizeof(float), stream);

    // ones-scatter + degree count (fused)
    k_edges0<<<(E + B - 1) / B, B, 0, stream>>>(src, dst, (float*)d_out, deg, E, N);

    // conv1 aggregation (norm inline)
    {
        long work = (long)E * F1;
        k_conv1_edges<<<(int)((work + B - 1) / B), B, 0, stream>>>(src, dst, deg, W1, x1, E);
    }
    // layer1: relu + 16x8 matmul, (node, feature)-parallel
    k_layer1<<<(N * F2 + B - 1) / B, B, 0, stream>>>(deg, b1, W1, W2, x1, h2, N);

    // conv2 aggregation (norm inline)
    {
        long work = (long)E * F2;
        k_conv2_edges<<<(int)((work + B - 1) / B), B, 0, stream>>>(src, dst, deg, h2, x2, E);
    }

    // orient scoring + scatter (conv2 self term + bias + relu inline)
    k_orient<<<(U + B - 1) / B, B, 0, stream>>>(und, x2, h2, deg, b2, Wfc, bfc,
                                                (float*)d_out, U, N);
}